// Round 16
// baseline (4294.102 us; speedup 1.0000x reference)
//
#include <hip/hip_runtime.h>
#include <math.h>

#define B_SZ   4096
#define T_SZ   60
#define F_SZ   30
#define H_ENC  256
#define HD_DEC 100
#define LATD   256
#define KTOT   288   // [seq 30 + pad2 ; h 256]
#define DEC_IN 279   // 256 + 9 + 14
#define DEC_IN_P 280
#define DTAIL  24    // dlq 9 + mp 14 + pad 1 (k = 256..279 of decinp)

// ---------------- workspace layout (float offsets) ----------------
enum {
  OFF_PW_F  = 0,                            // 288*256 float4 (gate-interleaved)
  OFF_PW_B  = OFF_PW_F + 288*256*4,
  OFF_A0F   = OFF_PW_B + 288*256*4,         // acq/date gate tables, [vocab][256]f4
  OFF_A1F   = OFF_A0F + 50*1024,
  OFF_A2F   = OFF_A1F + 10*1024,
  OFF_T0F   = OFF_A2F + 5*1024,
  OFF_T1F   = OFF_T0F + 30*1024,
  OFF_T2F   = OFF_T1F + 12*1024,
  OFF_A0B   = OFF_T2F + 31*1024,
  OFF_A1B   = OFF_A0B + 50*1024,
  OFF_A2B   = OFF_A1B + 10*1024,
  OFF_T0B   = OFF_A2B + 5*1024,
  OFF_T1B   = OFF_T0B + 30*1024,
  OFF_T2B   = OFF_T1B + 12*1024,
  OFF_PLAT  = OFF_T2B + 31*1024,            // 256*256 float2 {mu,lv}
  OFF_P1I   = OFF_PLAT + 256*256*2,         // 280*100 float4
  OFF_P1H   = OFF_P1I + 280*100*4,
  OFF_P2I   = OFF_P1H + 100*100*4,
  OFF_P2H   = OFF_P2I + 100*100*4,
  OFF_WG1T  = OFF_P2H + 100*100*4,          // [100][25]
  OFF_BE_F  = OFF_WG1T + 100*25,            // [1024]
  OFF_BE_B  = OFF_BE_F + 1024,
  OFF_BE1   = OFF_BE_B + 1024,              // [400]
  OFF_BE2   = OFF_BE1 + 400,
  OFF_HF    = OFF_BE2 + 400,                // [4096][256]
  OFF_HB    = OFF_HF + B_SZ*H_ENC,
  OFF_Z     = OFF_HB + B_SZ*H_ENC,
  OFF_H1    = OFF_Z + B_SZ*LATD,
  OFF_C1    = OFF_H1 + B_SZ*HD_DEC,
  OFF_H2    = OFF_C1 + B_SZ*HD_DEC,
  OFF_C2    = OFF_H2 + B_SZ*HD_DEC,
  OFF_DLQ   = OFF_C2 + B_SZ*HD_DEC,
  OFF_XBUF  = OFF_DLQ + B_SZ*9,
  OFF_MU    = OFF_XBUF + B_SZ*25,
  OFF_RSTD  = OFF_MU + 25,
  OFF_ZW1   = OFF_RSTD + 25,                // [4096][400] z @ Wih1[:, :256].T
  WS_FLOATS = OFF_ZW1 + B_SZ*400
};

__device__ __forceinline__ float sigf(float x) { return 1.0f / (1.0f + expf(-x)); }

// ---------------- prep: packs, bias sums, embed-gate tables ----------------
// mode 0 pack:  dst[(k*U+u)*G+g] = k<C ? a[(g*U+u)*C+k] : 0        (U=p0,C=p1,Kp=p2,G=p3)
// mode 1 bias:  dst[i] = a[i]+b[i], i<p0
// mode 2 enc:   a=Wih[.][74], b=Whh[.][256] -> dst[288][256]f4 (k<30 seq, 30..31 zero, 32+ h)
// mode 3 table: a=E[p0][p1], b=Wih raw, off=p2 -> dst[p0][256]f4 = E @ Wih[:, off:off+p1]
struct PJob { const float* a; const float* b; float* dst; int p0, p1, p2, p3, mode; };
struct PrepArgs { PJob j[24]; };

__global__ __launch_bounds__(256) void prep_kernel(PrepArgs pa) {
  int gtid = blockIdx.x * blockDim.x + threadIdx.x;
  int stride = gridDim.x * blockDim.x;
  for (int jj = 0; jj < 24; ++jj) {
    PJob jb = pa.j[jj];
    if (jb.mode == 1) {
      for (int i = gtid; i < jb.p0; i += stride) jb.dst[i] = jb.a[i] + jb.b[i];
    } else if (jb.mode == 0) {
      int total = jb.p2 * jb.p0;
      for (int i = gtid; i < total; i += stride) {
        int k = i / jb.p0, u = i - k * jb.p0;
        float* d = jb.dst + (size_t)i * jb.p3;
        for (int g = 0; g < jb.p3; ++g)
          d[g] = (k < jb.p1) ? jb.a[(g * jb.p0 + u) * jb.p1 + k] : 0.0f;
      }
    } else if (jb.mode == 2) {
      int total = KTOT * 256;
      for (int i = gtid; i < total; i += stride) {
        int k = i >> 8, u = i & 255;
        float* d = jb.dst + (size_t)i * 4;
        for (int g = 0; g < 4; ++g) {
          float v;
          if (k < 30)      v = jb.a[(g * 256 + u) * 74 + k];
          else if (k < 32) v = 0.0f;
          else             v = jb.b[(g * 256 + u) * 256 + (k - 32)];
          d[g] = v;
        }
      }
    } else {
      int total = jb.p0 * 256;
      for (int i = gtid; i < total; i += stride) {
        int v = i >> 8, u = i & 255;
        float* d = jb.dst + (size_t)i * 4;
        for (int g = 0; g < 4; ++g) {
          float s = 0.0f;
          for (int dd = 0; dd < jb.p1; ++dd)
            s += jb.a[v * jb.p1 + dd] * jb.b[(g * 256 + u) * 74 + jb.p2 + dd];
          d[g] = s;
        }
      }
    }
  }
}

#define GDOT(acc, c, w0, w1, w2, w3, xv) \
  acc = fmaf((w0).c, (xv).x, fmaf((w1).c, (xv).y, fmaf((w2).c, (xv).z, fmaf((w3).c, (xv).w, acc))))

// ---------------- encoder: 16 rows/block, 2 blocks/CU (2x occupancy) ----------
// 512 blocks: [0,256) fwd, [256,512) bwd; block c owns rows {c + 256*j : j=0..15}
// (globally sorted-desc seq_len => per-group quantile lengths {60,45,30,15},
// identical across blocks -> balance + taper preserved from r12).
// 1024 threads: u=tid&255 owns unit u; rq=tid>>8 -> rows [4rq,4rq+4).
// vs r12/r15 (32 rows, 1 blk/CU, Occ 45%): same total FMA/LDS work, but
// 2 blocks/CU -> 8 waves/SIMD latency hiding, and per-thread acc halves
// (16 regs) -> fits the 64-VGPR cap with slack for weight-load pipelining.
__global__ __launch_bounds__(1024) void enc_kernel(
    const float* __restrict__ seq, const int* __restrict__ seq_len,
    const int* __restrict__ ymd, const int* __restrict__ acq,
    const float4* __restrict__ PWf, const float4* __restrict__ PWb,
    const float4* __restrict__ A0f, const float4* __restrict__ A1f, const float4* __restrict__ A2f,
    const float4* __restrict__ T0f, const float4* __restrict__ T1f, const float4* __restrict__ T2f,
    const float4* __restrict__ A0b, const float4* __restrict__ A1b, const float4* __restrict__ A2b,
    const float4* __restrict__ T0b, const float4* __restrict__ T1b, const float4* __restrict__ T2b,
    const float* __restrict__ be_f, const float* __restrict__ be_b,
    float* __restrict__ hf_out, float* __restrict__ hb_out)
{
  const int tid = threadIdx.x;
  const bool bwd = blockIdx.x >= 256;
  const int c = blockIdx.x & 255;
  const float4* __restrict__ PW = bwd ? PWb : PWf;
  const float4* __restrict__ A0 = bwd ? A0b : A0f;
  const float4* __restrict__ A1 = bwd ? A1b : A1f;
  const float4* __restrict__ A2 = bwd ? A2b : A2f;
  const float4* __restrict__ T0 = bwd ? T0b : T0f;
  const float4* __restrict__ T1 = bwd ? T1b : T1f;
  const float4* __restrict__ T2 = bwd ? T2b : T2f;
  const float* __restrict__ be  = bwd ? be_b : be_f;
  float* __restrict__ hout = bwd ? hb_out : hf_out;

  __shared__ float v_s[16][KTOT];      // [0:30) seq, [30:32) zero pad, [32:288) h
  __shared__ int   len_s[16];
  __shared__ int   ids_s[16][3];       // per-step date ids
  __shared__ int   aqs_s[16][3];       // t-invariant acq ids

  for (int i = tid; i < 16 * KTOT; i += 1024) (&v_s[0][0])[i] = 0.0f;
  if (tid < 16) len_s[tid] = seq_len[c + 256 * tid];
  if (tid >= 64 && tid < 112) {        // 48 threads: acq ids
    int i = tid - 64;
    int r = i / 3, f = i - r * 3;
    aqs_s[r][f] = acq[(c + 256 * r) * 3 + f];
  }
  __syncthreads();

  const int u  = tid & 255;
  const int rq = tid >> 8;             // 0..3
  const int j0 = rq * 4;
  const float4* __restrict__ Wp = PW + u;

  const float bi0 = be[u], bi1 = be[256 + u], bi2 = be[512 + u], bi3 = be[768 + u];

  int   lenr[4];
  float cst[4];
  #pragma unroll
  for (int r = 0; r < 4; ++r) { cst[r] = 0.0f; lenr[r] = len_s[j0 + r]; }
  const int maxlen = len_s[0];
  const int mylen  = lenr[0];          // rows ranked desc within block

  for (int t = 0; t < maxlen; ++t) {
    // ---- stage seq features + date ids ----
    if (tid < 480) {                   // 16 rows * 30 feats
      int r = tid / 30, k = tid - r * 30;
      int len = len_s[r];
      int te = bwd ? max(len - 1 - t, 0) : t;
      v_s[r][k] = seq[((c + 256 * r) * T_SZ + te) * F_SZ + k];
    }
    if (tid >= 512 && tid < 560) {     // 48: 16 rows * 3 ids (diff wave than seq)
      int i = tid - 512;
      int r = i / 3, f = i - r * 3;
      int len = len_s[r];
      int te = bwd ? max(len - 1 - t, 0) : t;
      ids_s[r][f] = ymd[((c + 256 * r) * T_SZ + te) * 3 + f];
    }
    __syncthreads();                   // A: v(t) seq + ids ready, h(t-1) visible

    float4 g[4];
    const bool act = (t < mylen);      // wave-uniform group gate
    if (act) {
      #pragma unroll
      for (int r = 0; r < 4; ++r) {
        const int* id = ids_s[j0 + r];
        const int* aq = aqs_s[j0 + r];
        float4 a;
        a.x = bi0; a.y = bi1; a.z = bi2; a.w = bi3;
        float4 e;
        e = A0[aq[0] * 256 + u]; a.x += e.x; a.y += e.y; a.z += e.z; a.w += e.w;
        e = A1[aq[1] * 256 + u]; a.x += e.x; a.y += e.y; a.z += e.z; a.w += e.w;
        e = A2[aq[2] * 256 + u]; a.x += e.x; a.y += e.y; a.z += e.z; a.w += e.w;
        e = T0[id[0] * 256 + u]; a.x += e.x; a.y += e.y; a.z += e.z; a.w += e.w;
        e = T1[id[1] * 256 + u]; a.x += e.x; a.y += e.y; a.z += e.z; a.w += e.w;
        e = T2[id[2] * 256 + u]; a.x += e.x; a.y += e.y; a.z += e.z; a.w += e.w;
        g[r] = a;
      }

      for (int k = 0; k < KTOT; k += 4) {
        const float4 w0 = Wp[(k + 0) << 8];
        const float4 w1 = Wp[(k + 1) << 8];
        const float4 w2 = Wp[(k + 2) << 8];
        const float4 w3 = Wp[(k + 3) << 8];
        #pragma unroll
        for (int r = 0; r < 4; ++r) {
          const float4 xv = *reinterpret_cast<const float4*>(&v_s[j0 + r][k]);
          GDOT(g[r].x, x, w0, w1, w2, w3, xv);
          GDOT(g[r].y, y, w0, w1, w2, w3, xv);
          GDOT(g[r].z, z, w0, w1, w2, w3, xv);
          GDOT(g[r].w, w, w0, w1, w2, w3, xv);
        }
      }

      // ---- cell update (per-row masked); h stashed in g[r].x ----
      #pragma unroll
      for (int r = 0; r < 4; ++r) {
        if (t < lenr[r]) {
          float ig = sigf(g[r].x);
          float fg = sigf(g[r].y);
          float gg = tanhf(g[r].z);
          float og = sigf(g[r].w);
          float cn = fg * cst[r] + ig * gg;
          cst[r] = cn;
          g[r].x = og * tanhf(cn);
        }
      }
    }
    __syncthreads();                   // B: all reads of step t done
    if (act) {
      #pragma unroll
      for (int r = 0; r < 4; ++r) if (t < lenr[r]) v_s[j0 + r][32 + u] = g[r].x;
    }
  }

  __syncthreads();
  for (int i = tid; i < 16 * H_ENC; i += 1024) {
    int r = i >> 8, uu = i & 255;
    hout[(c + 256 * r) * H_ENC + uu] = v_s[r][32 + uu];
  }
}

// ---------------- latent ----------------
__global__ __launch_bounds__(256) void latent_kernel(
    const float* __restrict__ hf, const float* __restrict__ hb,
    const float2* __restrict__ Plat, const float* __restrict__ b_lat,
    const float* __restrict__ z_noise, const float* __restrict__ seq,
    const int* __restrict__ seq_len,
    float* __restrict__ z, float* __restrict__ dlq,
    float* __restrict__ h1w, float* __restrict__ c1w,
    float* __restrict__ h2w, float* __restrict__ c2w)
{
  const int tid = threadIdx.x;
  const int b0 = blockIdx.x * 16;
  __shared__ float hs[16][H_ENC];
  for (int i = tid; i < 16 * H_ENC; i += 256)
    (&hs[0][0])[i] = hf[b0 * H_ENC + i] + hb[b0 * H_ENC + i];
  __syncthreads();

  const int u = tid;
  const float bm = b_lat[u], bv = b_lat[LATD + u];
  float am[16], av[16];
  #pragma unroll
  for (int r = 0; r < 16; ++r) { am[r] = bm; av[r] = bv; }

  for (int k = 0; k < H_ENC; k += 4) {
    const float2 p0 = Plat[(k + 0) * 256 + u];
    const float2 p1 = Plat[(k + 1) * 256 + u];
    const float2 p2 = Plat[(k + 2) * 256 + u];
    const float2 p3 = Plat[(k + 3) * 256 + u];
    #pragma unroll
    for (int r = 0; r < 16; ++r) {
      const float4 hv = *reinterpret_cast<const float4*>(&hs[r][k]);
      am[r] = fmaf(p0.x, hv.x, fmaf(p1.x, hv.y, fmaf(p2.x, hv.z, fmaf(p3.x, hv.w, am[r]))));
      av[r] = fmaf(p0.y, hv.x, fmaf(p1.y, hv.y, fmaf(p2.y, hv.z, fmaf(p3.y, hv.w, av[r]))));
    }
  }
  #pragma unroll
  for (int r = 0; r < 16; ++r) {
    int b = b0 + r;
    z[b * LATD + u] = am[r] + sqrtf(expf(av[r])) * z_noise[b * LATD + u];
  }
  if (u < HD_DEC) {
    #pragma unroll
    for (int r = 0; r < 16; ++r) {
      int b = b0 + r;
      h1w[b * HD_DEC + u] = 0.0f; c1w[b * HD_DEC + u] = 0.0f;
      h2w[b * HD_DEC + u] = 0.0f; c2w[b * HD_DEC + u] = 0.0f;
    }
  }
  if (u < 9) {
    #pragma unroll
    for (int r = 0; r < 16; ++r) {
      int b = b0 + r;
      int len = seq_len[b];
      dlq[b * 9 + u] = seq[(b * T_SZ + (len - 1)) * F_SZ + 21 + u];
    }
  }
}

// ---------------- decoder z-precompute: zw1[b][400] = z @ Wih1[:, :256].T -----
__global__ __launch_bounds__(256) void dec_zpre_kernel(
    const float* __restrict__ z, const float4* __restrict__ P1I,
    float* __restrict__ zw1)
{
  const int tid = threadIdx.x;
  const int b0 = blockIdx.x * 16;
  __shared__ float zs[16][LATD];
  for (int i = tid; i < 16 * LATD; i += 256)
    (&zs[0][0])[i] = z[b0 * LATD + i];
  __syncthreads();

  const int u = tid & 127;
  const int grp = tid >> 7;       // 0/1 -> rows [0..8) / [8..16)
  const int r0 = grp * 8;
  if (u >= HD_DEC) return;

  float a0[8], a1[8], a2[8], a3[8];
  #pragma unroll
  for (int r = 0; r < 8; ++r) { a0[r] = 0.0f; a1[r] = 0.0f; a2[r] = 0.0f; a3[r] = 0.0f; }
  for (int k = 0; k < LATD; k += 4) {
    const float4 w0 = P1I[(k + 0) * 100 + u];
    const float4 w1 = P1I[(k + 1) * 100 + u];
    const float4 w2 = P1I[(k + 2) * 100 + u];
    const float4 w3 = P1I[(k + 3) * 100 + u];
    #pragma unroll
    for (int r = 0; r < 8; ++r) {
      const float4 xv = *reinterpret_cast<const float4*>(&zs[r0 + r][k]);
      GDOT(a0[r], x, w0, w1, w2, w3, xv);
      GDOT(a1[r], y, w0, w1, w2, w3, xv);
      GDOT(a2[r], z, w0, w1, w2, w3, xv);
      GDOT(a3[r], w, w0, w1, w2, w3, xv);
    }
  }
  #pragma unroll
  for (int r = 0; r < 8; ++r) {
    int b = b0 + r0 + r;
    zw1[b * 400 + u]       = a0[r];
    zw1[b * 400 + 100 + u] = a1[r];
    zw1[b * 400 + 200 + u] = a2[r];
    zw1[b * 400 + 300 + u] = a3[r];
  }
}

// ---------------- decoder cell step (z-part precomputed) ----------------
__global__ __launch_bounds__(256) void dec_cell_kernel(
    const float* __restrict__ zw1, const float* __restrict__ dlq,
    const float* __restrict__ macro,
    float* __restrict__ h1w, float* __restrict__ c1w,
    float* __restrict__ h2w, float* __restrict__ c2w,
    const float4* __restrict__ P1I, const float4* __restrict__ P1H, const float* __restrict__ be1,
    const float4* __restrict__ P2I, const float4* __restrict__ P2H, const float* __restrict__ be2,
    const float* __restrict__ Wg1T, const float* __restrict__ bg1,
    float* __restrict__ xbuf, int t)
{
  const int tid = threadIdx.x;
  const int b0 = blockIdx.x * 16;
  __shared__ float di[16][DTAIL];      // decinp k in [256..280): dlq 9 + mp 14 + pad
  __shared__ float h1s[16][HD_DEC];
  __shared__ float h2s[16][HD_DEC];

  for (int i = tid; i < 16 * DTAIL; i += 256) {
    int r = i / DTAIL, k = i - r * DTAIL;
    int b = b0 + r;
    float v;
    if (k < 9)       v = dlq[b * 9 + k];
    else if (k < 23) v = macro[(b * 12 + t) * 14 + (k - 9)];
    else             v = 0.0f;
    di[r][k] = v;
  }
  for (int i = tid; i < 16 * HD_DEC; i += 256) {
    int r = i / HD_DEC, k = i - r * HD_DEC;
    h1s[r][k] = h1w[(b0 + r) * HD_DEC + k];
    h2s[r][k] = h2w[(b0 + r) * HD_DEC + k];
  }

  const int u = tid & 127;
  const int grp = tid >> 7;       // 0/1 -> rows [0..8) / [8..16)
  const int r0 = grp * 8;
  const bool act = u < HD_DEC;

  float c1r[8], c2r[8];
  if (act) {
    #pragma unroll
    for (int r = 0; r < 8; ++r) {
      c1r[r] = c1w[(b0 + r0 + r) * HD_DEC + u];
      c2r[r] = c2w[(b0 + r0 + r) * HD_DEC + u];
    }
  }
  __syncthreads();

  // ---- LSTM1 gates: init = be1 + zw1 (z-part hoisted); k-loop over tail + h ----
  float a0[8], a1[8], a2[8], a3[8];
  if (act) {
    const float b0g = be1[u], b1g = be1[100 + u], b2g = be1[200 + u], b3g = be1[300 + u];
    #pragma unroll
    for (int r = 0; r < 8; ++r) {
      const float* zw = &zw1[(size_t)(b0 + r0 + r) * 400];
      a0[r] = b0g + zw[u];
      a1[r] = b1g + zw[100 + u];
      a2[r] = b2g + zw[200 + u];
      a3[r] = b3g + zw[300 + u];
    }
    for (int k = 0; k < DTAIL; k += 4) {
      const int kk = LATD + k;
      const float4 w0 = P1I[(kk + 0) * 100 + u];
      const float4 w1 = P1I[(kk + 1) * 100 + u];
      const float4 w2 = P1I[(kk + 2) * 100 + u];
      const float4 w3 = P1I[(kk + 3) * 100 + u];
      #pragma unroll
      for (int r = 0; r < 8; ++r) {
        const float4 xv = *reinterpret_cast<const float4*>(&di[r0 + r][k]);
        GDOT(a0[r], x, w0, w1, w2, w3, xv);
        GDOT(a1[r], y, w0, w1, w2, w3, xv);
        GDOT(a2[r], z, w0, w1, w2, w3, xv);
        GDOT(a3[r], w, w0, w1, w2, w3, xv);
      }
    }
    for (int k = 0; k < HD_DEC; k += 4) {
      const float4 w0 = P1H[(k + 0) * 100 + u];
      const float4 w1 = P1H[(k + 1) * 100 + u];
      const float4 w2 = P1H[(k + 2) * 100 + u];
      const float4 w3 = P1H[(k + 3) * 100 + u];
      #pragma unroll
      for (int r = 0; r < 8; ++r) {
        const float4 hv = *reinterpret_cast<const float4*>(&h1s[r0 + r][k]);
        GDOT(a0[r], x, w0, w1, w2, w3, hv);
        GDOT(a1[r], y, w0, w1, w2, w3, hv);
        GDOT(a2[r], z, w0, w1, w2, w3, hv);
        GDOT(a3[r], w, w0, w1, w2, w3, hv);
      }
    }
  }
  __syncthreads();                 // h1s reads complete
  if (act) {
    #pragma unroll
    for (int r = 0; r < 8; ++r) {
      float ig = sigf(a0[r]), fg = sigf(a1[r]), gg = tanhf(a2[r]), og = sigf(a3[r]);
      float cn = fg * c1r[r] + ig * gg;
      float hn = og * tanhf(cn);
      int b = b0 + r0 + r;
      h1s[r0 + r][u] = hn;
      h1w[b * HD_DEC + u] = hn;
      c1w[b * HD_DEC + u] = cn;
    }
  }
  __syncthreads();                 // new h1 visible

  // ---- LSTM2 gates (x = new h1, h = old h2) ----
  if (act) {
    const float b0g = be2[u], b1g = be2[100 + u], b2g = be2[200 + u], b3g = be2[300 + u];
    #pragma unroll
    for (int r = 0; r < 8; ++r) { a0[r] = b0g; a1[r] = b1g; a2[r] = b2g; a3[r] = b3g; }
    for (int k = 0; k < HD_DEC; k += 4) {
      const float4 w0 = P2I[(k + 0) * 100 + u];
      const float4 w1 = P2I[(k + 1) * 100 + u];
      const float4 w2 = P2I[(k + 2) * 100 + u];
      const float4 w3 = P2I[(k + 3) * 100 + u];
      #pragma unroll
      for (int r = 0; r < 8; ++r) {
        const float4 hv = *reinterpret_cast<const float4*>(&h1s[r0 + r][k]);
        GDOT(a0[r], x, w0, w1, w2, w3, hv);
        GDOT(a1[r], y, w0, w1, w2, w3, hv);
        GDOT(a2[r], z, w0, w1, w2, w3, hv);
        GDOT(a3[r], w, w0, w1, w2, w3, hv);
      }
    }
    for (int k = 0; k < HD_DEC; k += 4) {
      const float4 w0 = P2H[(k + 0) * 100 + u];
      const float4 w1 = P2H[(k + 1) * 100 + u];
      const float4 w2 = P2H[(k + 2) * 100 + u];
      const float4 w3 = P2H[(k + 3) * 100 + u];
      #pragma unroll
      for (int r = 0; r < 8; ++r) {
        const float4 hv = *reinterpret_cast<const float4*>(&h2s[r0 + r][k]);
        GDOT(a0[r], x, w0, w1, w2, w3, hv);
        GDOT(a1[r], y, w0, w1, w2, w3, hv);
        GDOT(a2[r], z, w0, w1, w2, w3, hv);
        GDOT(a3[r], w, w0, w1, w2, w3, hv);
      }
    }
  }
  __syncthreads();                 // h2s reads complete
  if (act) {
    #pragma unroll
    for (int r = 0; r < 8; ++r) {
      float ig = sigf(a0[r]), fg = sigf(a1[r]), gg = tanhf(a2[r]), og = sigf(a3[r]);
      float cn = fg * c2r[r] + ig * gg;
      float hn = og * tanhf(cn);
      int b = b0 + r0 + r;
      h2s[r0 + r][u] = hn;
      h2w[b * HD_DEC + u] = hn;
      c2w[b * HD_DEC + u] = cn;
    }
  }
  __syncthreads();                 // new h2 visible

  // ---- x = relu(h2 @ Wg1T + bg1) ----
  for (int p = tid; p < 16 * 25; p += 256) {
    int r = p / 25, cc = p - r * 25;
    float s = bg1[cc];
    for (int k = 0; k < HD_DEC; k += 4) {
      const float4 hv = *reinterpret_cast<const float4*>(&h2s[r][k]);
      s += hv.x * Wg1T[k * 25 + cc] + hv.y * Wg1T[(k + 1) * 25 + cc]
         + hv.z * Wg1T[(k + 2) * 25 + cc] + hv.w * Wg1T[(k + 3) * 25 + cc];
    }
    xbuf[(b0 + r) * 25 + cc] = fmaxf(s, 0.0f);
  }
}

// ---------------- decoder batchnorm stats ----------------
__global__ __launch_bounds__(256) void dec_stats_kernel(
    const float* __restrict__ xbuf, float* __restrict__ muv, float* __restrict__ rstdv)
{
  const int col = blockIdx.x;
  const int tid = threadIdx.x;
  __shared__ float red[256];
  float v[16];
  float s = 0.0f;
  #pragma unroll
  for (int i = 0; i < 16; ++i) { v[i] = xbuf[(tid + 256 * i) * 25 + col]; s += v[i]; }
  red[tid] = s; __syncthreads();
  for (int off = 128; off >= 1; off >>= 1) {
    if (tid < off) red[tid] += red[tid + off];
    __syncthreads();
  }
  float mean = red[0] / (float)B_SZ;
  __syncthreads();
  float s2 = 0.0f;
  #pragma unroll
  for (int i = 0; i < 16; ++i) { float d = v[i] - mean; s2 += d * d; }
  red[tid] = s2; __syncthreads();
  for (int off = 128; off >= 1; off >>= 1) {
    if (tid < off) red[tid] += red[tid + off];
    __syncthreads();
  }
  if (tid == 0) {
    muv[col] = mean;
    rstdv[col] = rsqrtf(red[0] / (float)B_SZ + 1e-5f);
  }
}

// ---------------- decoder normalize + output ----------------
__global__ __launch_bounds__(256) void dec_out_kernel(
    const float* __restrict__ xbuf, const float* __restrict__ muv, const float* __restrict__ rstdv,
    const float* __restrict__ gamma, const float* __restrict__ beta,
    const float* __restrict__ Wg2, const float* __restrict__ bg2,
    float* __restrict__ dlq, float* __restrict__ out, int t)
{
  int b = blockIdx.x * 256 + threadIdx.x;
  float xn[25];
  #pragma unroll
  for (int c = 0; c < 25; ++c)
    xn[c] = gamma[c] * (xbuf[b * 25 + c] - muv[c]) * rstdv[c] + beta[c];
  #pragma unroll
  for (int j = 0; j < 9; ++j) {
    float s = bg2[j];
    #pragma unroll
    for (int c = 0; c < 25; ++c) s += xn[c] * Wg2[j * 25 + c];
    dlq[b * 9 + j] = s;
    out[b * 108 + j * 12 + t] = s;
  }
}

// ---------------- host launch ----------------
extern "C" void kernel_launch(void* const* d_in, const int* in_sizes, int n_in,
                              void* d_out, int out_size, void* d_ws, size_t ws_size,
                              hipStream_t stream)
{
  const float* seq     = (const float*)d_in[0];
  const int*   seq_len = (const int*)  d_in[1];
  const int*   ymd     = (const int*)  d_in[2];
  const int*   acq     = (const int*)  d_in[3];
  const float* macro   = (const float*)d_in[4];
  const float* z_noise = (const float*)d_in[5];
  const float* Ea0 = (const float*)d_in[6];
  const float* Ea1 = (const float*)d_in[7];
  const float* Ea2 = (const float*)d_in[8];
  const float* Es0 = (const float*)d_in[9];
  const float* Es1 = (const float*)d_in[10];
  const float* Es2 = (const float*)d_in[11];
  const float* Wih_f = (const float*)d_in[12];
  const float* Whh_f = (const float*)d_in[13];
  const float* bih_f = (const float*)d_in[14];
  const float* bhh_f = (const float*)d_in[15];
  const float* Wih_b = (const float*)d_in[16];
  const float* Whh_b = (const float*)d_in[17];
  const float* bih_b = (const float*)d_in[18];
  const float* bhh_b = (const float*)d_in[19];
  const float* W_lat = (const float*)d_in[20];
  const float* b_lat = (const float*)d_in[21];
  const float* Wih1  = (const float*)d_in[22];
  const float* Whh1  = (const float*)d_in[23];
  const float* bih1  = (const float*)d_in[24];
  const float* bhh1  = (const float*)d_in[25];
  const float* Wih2  = (const float*)d_in[26];
  const float* Whh2  = (const float*)d_in[27];
  const float* bih2  = (const float*)d_in[28];
  const float* bhh2  = (const float*)d_in[29];
  const float* Wg1   = (const float*)d_in[30];
  const float* bg1   = (const float*)d_in[31];
  const float* gamma = (const float*)d_in[32];
  const float* beta  = (const float*)d_in[33];
  const float* Wg2   = (const float*)d_in[34];
  const float* bg2   = (const float*)d_in[35];

  float* ws  = (float*)d_ws;
  float* out = (float*)d_out;

  float* pwF  = ws + OFF_PW_F;
  float* pwB  = ws + OFF_PW_B;
  float* a0F  = ws + OFF_A0F;  float* a1F = ws + OFF_A1F;  float* a2F = ws + OFF_A2F;
  float* t0F  = ws + OFF_T0F;  float* t1F = ws + OFF_T1F;  float* t2F = ws + OFF_T2F;
  float* a0B  = ws + OFF_A0B;  float* a1B = ws + OFF_A1B;  float* a2B = ws + OFF_A2B;
  float* t0B  = ws + OFF_T0B;  float* t1B = ws + OFF_T1B;  float* t2B = ws + OFF_T2B;
  float* plat = ws + OFF_PLAT;
  float* p1i  = ws + OFF_P1I;
  float* p1h  = ws + OFF_P1H;
  float* p2i  = ws + OFF_P2I;
  float* p2h  = ws + OFF_P2H;
  float* wg1T = ws + OFF_WG1T;
  float* be_f = ws + OFF_BE_F;
  float* be_b = ws + OFF_BE_B;
  float* be1  = ws + OFF_BE1;
  float* be2  = ws + OFF_BE2;
  float* hf   = ws + OFF_HF;
  float* hb   = ws + OFF_HB;
  float* z    = ws + OFF_Z;
  float* h1w  = ws + OFF_H1;
  float* c1w  = ws + OFF_C1;
  float* h2w  = ws + OFF_H2;
  float* c2w  = ws + OFF_C2;
  float* dlq  = ws + OFF_DLQ;
  float* xbuf = ws + OFF_XBUF;
  float* muv  = ws + OFF_MU;
  float* rstdv= ws + OFF_RSTD;
  float* zw1  = ws + OFF_ZW1;

  PrepArgs pa;
  int ji = 0;
  auto JOB = [&](const float* a, const float* b, float* d, int p0, int p1, int p2, int p3, int m) {
    pa.j[ji].a = a; pa.j[ji].b = b; pa.j[ji].dst = d;
    pa.j[ji].p0 = p0; pa.j[ji].p1 = p1; pa.j[ji].p2 = p2; pa.j[ji].p3 = p3; pa.j[ji].mode = m; ++ji;
  };
  JOB(Wih_f, Whh_f, pwF, 0,0,0,0, 2);
  JOB(Wih_b, Whh_b, pwB, 0,0,0,0, 2);
  JOB(Ea0, Wih_f, a0F, 50, 16, 30, 0, 3);
  JOB(Ea1, Wih_f, a1F, 10,  8, 46, 0, 3);
  JOB(Ea2, Wih_f, a2F,  5,  4, 54, 0, 3);
  JOB(Es0, Wih_f, t0F, 30,  8, 58, 0, 3);
  JOB(Es1, Wih_f, t1F, 12,  4, 66, 0, 3);
  JOB(Es2, Wih_f, t2F, 31,  4, 70, 0, 3);
  JOB(Ea0, Wih_b, a0B, 50, 16, 30, 0, 3);
  JOB(Ea1, Wih_b, a1B, 10,  8, 46, 0, 3);
  JOB(Ea2, Wih_b, a2B,  5,  4, 54, 0, 3);
  JOB(Es0, Wih_b, t0B, 30,  8, 58, 0, 3);
  JOB(Es1, Wih_b, t1B, 12,  4, 66, 0, 3);
  JOB(Es2, Wih_b, t2B, 31,  4, 70, 0, 3);
  JOB(W_lat, nullptr, plat, 256, 256, 256, 2, 0);
  JOB(Wih1,  nullptr, p1i,  100, 279, 280, 4, 0);
  JOB(Whh1,  nullptr, p1h,  100, 100, 100, 4, 0);
  JOB(Wih2,  nullptr, p2i,  100, 100, 100, 4, 0);
  JOB(Whh2,  nullptr, p2h,  100, 100, 100, 4, 0);
  JOB(Wg1,   nullptr, wg1T, 25, 100, 100, 1, 0);
  JOB(bih_f, bhh_f, be_f, 1024, 0,0,0, 1);
  JOB(bih_b, bhh_b, be_b, 1024, 0,0,0, 1);
  JOB(bih1,  bhh1,  be1,  400, 0,0,0, 1);
  JOB(bih2,  bhh2,  be2,  400, 0,0,0, 1);

  prep_kernel<<<512, 256, 0, stream>>>(pa);

  enc_kernel<<<512, 1024, 0, stream>>>(
      seq, seq_len, ymd, acq,
      (const float4*)pwF, (const float4*)pwB,
      (const float4*)a0F, (const float4*)a1F, (const float4*)a2F,
      (const float4*)t0F, (const float4*)t1F, (const float4*)t2F,
      (const float4*)a0B, (const float4*)a1B, (const float4*)a2B,
      (const float4*)t0B, (const float4*)t1B, (const float4*)t2B,
      be_f, be_b, hf, hb);

  latent_kernel<<<256, 256, 0, stream>>>(
      hf, hb, (const float2*)plat, b_lat, z_noise, seq, seq_len,
      z, dlq, h1w, c1w, h2w, c2w);

  dec_zpre_kernel<<<256, 256, 0, stream>>>(z, (const float4*)p1i, zw1);

  for (int t = 0; t < 12; ++t) {
    dec_cell_kernel<<<256, 256, 0, stream>>>(
        zw1, dlq, macro, h1w, c1w, h2w, c2w,
        (const float4*)p1i, (const float4*)p1h, be1,
        (const float4*)p2i, (const float4*)p2h, be2, wg1T, bg1, xbuf, t);
    dec_stats_kernel<<<25, 256, 0, stream>>>(xbuf, muv, rstdv);
    dec_out_kernel<<<16, 256, 0, stream>>>(
        xbuf, muv, rstdv, gamma, beta, Wg2, bg2, dlq, out, t);
  }
}

// Round 17
// 3566.034 us; speedup vs baseline: 1.2042x; 1.2042x over previous
//
#include <hip/hip_runtime.h>
#include <math.h>

#define B_SZ   4096
#define T_SZ   60
#define F_SZ   30
#define H_ENC  256
#define HD_DEC 100
#define LATD   256
#define KTOT   288   // [seq 30 + pad2 ; h 256]
#define KPAIR  144   // KTOT/2 bf16-packed pairs
#define DEC_IN 279   // 256 + 9 + 14
#define DEC_IN_P 280
#define DTAIL  24    // dlq 9 + mp 14 + pad 1 (k = 256..279 of decinp)

// ---------------- workspace layout (float offsets) ----------------
enum {
  OFF_PW_F  = 0,                            // bf16-packed: 144*256 uint4 (uses half)
  OFF_PW_B  = OFF_PW_F + 288*256*4,
  OFF_A0F   = OFF_PW_B + 288*256*4,         // acq/date gate tables, [vocab][256]f4
  OFF_A1F   = OFF_A0F + 50*1024,
  OFF_A2F   = OFF_A1F + 10*1024,
  OFF_T0F   = OFF_A2F + 5*1024,
  OFF_T1F   = OFF_T0F + 30*1024,
  OFF_T2F   = OFF_T1F + 12*1024,
  OFF_A0B   = OFF_T2F + 31*1024,
  OFF_A1B   = OFF_A0B + 50*1024,
  OFF_A2B   = OFF_A1B + 10*1024,
  OFF_T0B   = OFF_A2B + 5*1024,
  OFF_T1B   = OFF_T0B + 30*1024,
  OFF_T2B   = OFF_T1B + 12*1024,
  OFF_PLAT  = OFF_T2B + 31*1024,            // 256*256 float2 {mu,lv}
  OFF_P1I   = OFF_PLAT + 256*256*2,         // 280*100 float4
  OFF_P1H   = OFF_P1I + 280*100*4,
  OFF_P2I   = OFF_P1H + 100*100*4,
  OFF_P2H   = OFF_P2I + 100*100*4,
  OFF_WG1T  = OFF_P2H + 100*100*4,          // [100][25]
  OFF_BE_F  = OFF_WG1T + 100*25,            // [1024]
  OFF_BE_B  = OFF_BE_F + 1024,
  OFF_BE1   = OFF_BE_B + 1024,              // [400]
  OFF_BE2   = OFF_BE1 + 400,
  OFF_HF    = OFF_BE2 + 400,                // [4096][256]
  OFF_HB    = OFF_HF + B_SZ*H_ENC,
  OFF_Z     = OFF_HB + B_SZ*H_ENC,
  OFF_H1    = OFF_Z + B_SZ*LATD,
  OFF_C1    = OFF_H1 + B_SZ*HD_DEC,
  OFF_H2    = OFF_C1 + B_SZ*HD_DEC,
  OFF_C2    = OFF_H2 + B_SZ*HD_DEC,
  OFF_DLQ   = OFF_C2 + B_SZ*HD_DEC,
  OFF_XBUF  = OFF_DLQ + B_SZ*9,
  OFF_MU    = OFF_XBUF + B_SZ*25,
  OFF_RSTD  = OFF_MU + 25,
  OFF_ZW1   = OFF_RSTD + 25,                // [4096][400] z @ Wih1[:, :256].T
  WS_FLOATS = OFF_ZW1 + B_SZ*400
};

__device__ __forceinline__ float sigf(float x) { return 1.0f / (1.0f + expf(-x)); }

__device__ __forceinline__ unsigned short f2bf(float f) {
  union { float f; unsigned int u; } v; v.f = f;
  unsigned int u = v.u + 0x7fffu + ((v.u >> 16) & 1u);
  return (unsigned short)(u >> 16);
}
__device__ __forceinline__ float2 bfpair(unsigned int w) {
  union { unsigned int u; float f; } a, b;
  a.u = w << 16; b.u = w & 0xffff0000u;
  float2 r; r.x = a.f; r.y = b.f; return r;
}

// ---------------- prep: packs, bias sums, embed-gate tables ----------------
// mode 0 pack:  dst[(k*U+u)*G+g] = k<C ? a[(g*U+u)*C+k] : 0        (U=p0,C=p1,Kp=p2,G=p3)
// mode 1 bias:  dst[i] = a[i]+b[i], i<p0
// mode 2 enc bf16-pack: a=Wih[.][74], b=Whh[.][256] ->
//   dst[pair m][u] = uint4; word g = bf16(W(2m,u,g)) | bf16(W(2m+1,u,g))<<16
//   where W(k,u,g) = k<30 ? Wih[g*256+u][k] : k<32 ? 0 : Whh[g*256+u][k-32]
// mode 3 table: a=E[p0][p1], b=Wih raw, off=p2 -> dst[p0][256]f4 = E @ Wih[:, off:off+p1]
struct PJob { const float* a; const float* b; float* dst; int p0, p1, p2, p3, mode; };
struct PrepArgs { PJob j[24]; };

__device__ __forceinline__ float enc_wval(const float* wih, const float* whh, int k, int u, int g) {
  if (k < 30)  return wih[(g * 256 + u) * 74 + k];
  if (k < 32)  return 0.0f;
  return whh[(g * 256 + u) * 256 + (k - 32)];
}

__global__ __launch_bounds__(256) void prep_kernel(PrepArgs pa) {
  int gtid = blockIdx.x * blockDim.x + threadIdx.x;
  int stride = gridDim.x * blockDim.x;
  for (int jj = 0; jj < 24; ++jj) {
    PJob jb = pa.j[jj];
    if (jb.mode == 1) {
      for (int i = gtid; i < jb.p0; i += stride) jb.dst[i] = jb.a[i] + jb.b[i];
    } else if (jb.mode == 0) {
      int total = jb.p2 * jb.p0;
      for (int i = gtid; i < total; i += stride) {
        int k = i / jb.p0, u = i - k * jb.p0;
        float* d = jb.dst + (size_t)i * jb.p3;
        for (int g = 0; g < jb.p3; ++g)
          d[g] = (k < jb.p1) ? jb.a[(g * jb.p0 + u) * jb.p1 + k] : 0.0f;
      }
    } else if (jb.mode == 2) {
      int total = KPAIR * 256;
      for (int i = gtid; i < total; i += stride) {
        int m = i >> 8, u = i & 255;
        unsigned int* d = (unsigned int*)jb.dst + (size_t)i * 4;
        for (int g = 0; g < 4; ++g) {
          float lo = enc_wval(jb.a, jb.b, 2 * m,     u, g);
          float hi = enc_wval(jb.a, jb.b, 2 * m + 1, u, g);
          d[g] = (unsigned int)f2bf(lo) | ((unsigned int)f2bf(hi) << 16);
        }
      }
    } else {
      int total = jb.p0 * 256;
      for (int i = gtid; i < total; i += stride) {
        int v = i >> 8, u = i & 255;
        float* d = jb.dst + (size_t)i * 4;
        for (int g = 0; g < 4; ++g) {
          float s = 0.0f;
          for (int dd = 0; dd < jb.p1; ++dd)
            s += jb.a[v * jb.p1 + dd] * jb.b[(g * 256 + u) * 74 + jb.p2 + dd];
          d[g] = s;
        }
      }
    }
  }
}

#define GDOT(acc, c, w0, w1, w2, w3, xv) \
  acc = fmaf((w0).c, (xv).x, fmaf((w1).c, (xv).y, fmaf((w2).c, (xv).z, fmaf((w3).c, (xv).w, acc))))

// ---------------- encoder: r15 geometry + bf16-packed weights ----------------
// 256 blocks: [0,128) fwd, [128,256) bwd; block c owns rows {c + 128*j : j=0..31}.
// 1024 threads: u=tid&255 owns unit u; rq=tid>>8 -> rows [8rq,8rq+8).
// Weights bf16-packed (2 k-slices / 16B): 2 VMEM loads per quad (was 4) ->
// weight bytes & load count halve; +16 shift/mask VALU per quad (12.5% of FMA).
// Inputs/h/c stay fp32. hipcc pins 1024-thr blocks at 64 VGPR; transients only.
__global__ __launch_bounds__(1024) void enc_kernel(
    const float* __restrict__ seq, const int* __restrict__ seq_len,
    const int* __restrict__ ymd, const int* __restrict__ acq,
    const uint4* __restrict__ PWf, const uint4* __restrict__ PWb,
    const float4* __restrict__ A0f, const float4* __restrict__ A1f, const float4* __restrict__ A2f,
    const float4* __restrict__ T0f, const float4* __restrict__ T1f, const float4* __restrict__ T2f,
    const float4* __restrict__ A0b, const float4* __restrict__ A1b, const float4* __restrict__ A2b,
    const float4* __restrict__ T0b, const float4* __restrict__ T1b, const float4* __restrict__ T2b,
    const float* __restrict__ be_f, const float* __restrict__ be_b,
    float* __restrict__ hf_out, float* __restrict__ hb_out)
{
  const int tid = threadIdx.x;
  const bool bwd = blockIdx.x >= 128;
  const int c = blockIdx.x & 127;
  const uint4* __restrict__ PW = bwd ? PWb : PWf;
  const float4* __restrict__ A0 = bwd ? A0b : A0f;
  const float4* __restrict__ A1 = bwd ? A1b : A1f;
  const float4* __restrict__ A2 = bwd ? A2b : A2f;
  const float4* __restrict__ T0 = bwd ? T0b : T0f;
  const float4* __restrict__ T1 = bwd ? T1b : T1f;
  const float4* __restrict__ T2 = bwd ? T2b : T2f;
  const float* __restrict__ be  = bwd ? be_b : be_f;
  float* __restrict__ hout = bwd ? hb_out : hf_out;

  __shared__ float v_s[32][KTOT];      // [0:30) seq, [30:32) zero pad, [32:288) h
  __shared__ int   len_s[32];
  __shared__ int   ids_s[32][3];       // per-step date ids
  __shared__ int   aqs_s[32][3];       // t-invariant acq ids

  for (int i = tid; i < 32 * KTOT; i += 1024) (&v_s[0][0])[i] = 0.0f;
  if (tid < 32) len_s[tid] = seq_len[c + 128 * tid];
  if (tid >= 64 && tid < 160) {        // 96 threads: acq ids
    int i = tid - 64;
    int r = i / 3, f = i - r * 3;
    aqs_s[r][f] = acq[(c + 128 * r) * 3 + f];
  }
  __syncthreads();

  const int u  = tid & 255;
  const int rq = tid >> 8;             // 0..3
  const int j0 = rq * 8;
  const uint4* __restrict__ Wp = PW + u;

  const float bi0 = be[u], bi1 = be[256 + u], bi2 = be[512 + u], bi3 = be[768 + u];

  int   lenr[8];
  float cst[8];
  #pragma unroll
  for (int r = 0; r < 8; ++r) { cst[r] = 0.0f; lenr[r] = len_s[j0 + r]; }
  const int maxlen = len_s[0];
  const int mylen  = lenr[0];          // rows ranked desc within block

  for (int t = 0; t < maxlen; ++t) {
    // ---- stage seq features + date ids ----
    if (tid < 960) {
      int r = tid / 30, k = tid - r * 30;
      int len = len_s[r];
      int te = bwd ? max(len - 1 - t, 0) : t;
      v_s[r][k] = seq[((c + 128 * r) * T_SZ + te) * F_SZ + k];
    }
    if (tid < 96) {
      int r = tid / 3, f = tid - r * 3;
      int len = len_s[r];
      int te = bwd ? max(len - 1 - t, 0) : t;
      ids_s[r][f] = ymd[((c + 128 * r) * T_SZ + te) * 3 + f];
    }
    __syncthreads();                   // A: v(t) seq + ids ready, h(t-1) visible

    float4 g[8];
    const bool act = (t < mylen);      // wave-uniform group gate
    if (act) {
      #pragma unroll
      for (int r = 0; r < 8; ++r) {
        const int* id = ids_s[j0 + r];
        const int* aq = aqs_s[j0 + r];
        float4 a;
        a.x = bi0; a.y = bi1; a.z = bi2; a.w = bi3;
        float4 e;
        e = A0[aq[0] * 256 + u]; a.x += e.x; a.y += e.y; a.z += e.z; a.w += e.w;
        e = A1[aq[1] * 256 + u]; a.x += e.x; a.y += e.y; a.z += e.z; a.w += e.w;
        e = A2[aq[2] * 256 + u]; a.x += e.x; a.y += e.y; a.z += e.z; a.w += e.w;
        e = T0[id[0] * 256 + u]; a.x += e.x; a.y += e.y; a.z += e.z; a.w += e.w;
        e = T1[id[1] * 256 + u]; a.x += e.x; a.y += e.y; a.z += e.z; a.w += e.w;
        e = T2[id[2] * 256 + u]; a.x += e.x; a.y += e.y; a.z += e.z; a.w += e.w;
        g[r] = a;
      }

      for (int m = 0; m < KPAIR; m += 2) {       // pair m: k=2m,2m+1
        const uint4 wa = Wp[(size_t)m << 8];
        const uint4 wb = Wp[(size_t)(m + 1) << 8];
        float4 w0, w1, w2, w3;
        float2 p;
        p = bfpair(wa.x); w0.x = p.x; w1.x = p.y;
        p = bfpair(wa.y); w0.y = p.x; w1.y = p.y;
        p = bfpair(wa.z); w0.z = p.x; w1.z = p.y;
        p = bfpair(wa.w); w0.w = p.x; w1.w = p.y;
        p = bfpair(wb.x); w2.x = p.x; w3.x = p.y;
        p = bfpair(wb.y); w2.y = p.x; w3.y = p.y;
        p = bfpair(wb.z); w2.z = p.x; w3.z = p.y;
        p = bfpair(wb.w); w2.w = p.x; w3.w = p.y;
        const int k = 2 * m;
        #pragma unroll
        for (int r = 0; r < 8; ++r) {
          const float4 xv = *reinterpret_cast<const float4*>(&v_s[j0 + r][k]);
          GDOT(g[r].x, x, w0, w1, w2, w3, xv);
          GDOT(g[r].y, y, w0, w1, w2, w3, xv);
          GDOT(g[r].z, z, w0, w1, w2, w3, xv);
          GDOT(g[r].w, w, w0, w1, w2, w3, xv);
        }
      }

      // ---- cell update (per-row masked); h stashed in g[r].x ----
      #pragma unroll
      for (int r = 0; r < 8; ++r) {
        if (t < lenr[r]) {
          float ig = sigf(g[r].x);
          float fg = sigf(g[r].y);
          float gg = tanhf(g[r].z);
          float og = sigf(g[r].w);
          float cn = fg * cst[r] + ig * gg;
          cst[r] = cn;
          g[r].x = og * tanhf(cn);
        }
      }
    }
    __syncthreads();                   // B: all reads of step t done
    if (act) {
      #pragma unroll
      for (int r = 0; r < 8; ++r) if (t < lenr[r]) v_s[j0 + r][32 + u] = g[r].x;
    }
  }

  __syncthreads();
  for (int i = tid; i < 32 * H_ENC; i += 1024) {
    int r = i >> 8, uu = i & 255;
    hout[(c + 128 * r) * H_ENC + uu] = v_s[r][32 + uu];
  }
}

// ---------------- latent ----------------
__global__ __launch_bounds__(256) void latent_kernel(
    const float* __restrict__ hf, const float* __restrict__ hb,
    const float2* __restrict__ Plat, const float* __restrict__ b_lat,
    const float* __restrict__ z_noise, const float* __restrict__ seq,
    const int* __restrict__ seq_len,
    float* __restrict__ z, float* __restrict__ dlq,
    float* __restrict__ h1w, float* __restrict__ c1w,
    float* __restrict__ h2w, float* __restrict__ c2w)
{
  const int tid = threadIdx.x;
  const int b0 = blockIdx.x * 16;
  __shared__ float hs[16][H_ENC];
  for (int i = tid; i < 16 * H_ENC; i += 256)
    (&hs[0][0])[i] = hf[b0 * H_ENC + i] + hb[b0 * H_ENC + i];
  __syncthreads();

  const int u = tid;
  const float bm = b_lat[u], bv = b_lat[LATD + u];
  float am[16], av[16];
  #pragma unroll
  for (int r = 0; r < 16; ++r) { am[r] = bm; av[r] = bv; }

  for (int k = 0; k < H_ENC; k += 4) {
    const float2 p0 = Plat[(k + 0) * 256 + u];
    const float2 p1 = Plat[(k + 1) * 256 + u];
    const float2 p2 = Plat[(k + 2) * 256 + u];
    const float2 p3 = Plat[(k + 3) * 256 + u];
    #pragma unroll
    for (int r = 0; r < 16; ++r) {
      const float4 hv = *reinterpret_cast<const float4*>(&hs[r][k]);
      am[r] = fmaf(p0.x, hv.x, fmaf(p1.x, hv.y, fmaf(p2.x, hv.z, fmaf(p3.x, hv.w, am[r]))));
      av[r] = fmaf(p0.y, hv.x, fmaf(p1.y, hv.y, fmaf(p2.y, hv.z, fmaf(p3.y, hv.w, av[r]))));
    }
  }
  #pragma unroll
  for (int r = 0; r < 16; ++r) {
    int b = b0 + r;
    z[b * LATD + u] = am[r] + sqrtf(expf(av[r])) * z_noise[b * LATD + u];
  }
  if (u < HD_DEC) {
    #pragma unroll
    for (int r = 0; r < 16; ++r) {
      int b = b0 + r;
      h1w[b * HD_DEC + u] = 0.0f; c1w[b * HD_DEC + u] = 0.0f;
      h2w[b * HD_DEC + u] = 0.0f; c2w[b * HD_DEC + u] = 0.0f;
    }
  }
  if (u < 9) {
    #pragma unroll
    for (int r = 0; r < 16; ++r) {
      int b = b0 + r;
      int len = seq_len[b];
      dlq[b * 9 + u] = seq[(b * T_SZ + (len - 1)) * F_SZ + 21 + u];
    }
  }
}

// ---------------- decoder z-precompute: zw1[b][400] = z @ Wih1[:, :256].T -----
__global__ __launch_bounds__(256) void dec_zpre_kernel(
    const float* __restrict__ z, const float4* __restrict__ P1I,
    float* __restrict__ zw1)
{
  const int tid = threadIdx.x;
  const int b0 = blockIdx.x * 16;
  __shared__ float zs[16][LATD];
  for (int i = tid; i < 16 * LATD; i += 256)
    (&zs[0][0])[i] = z[b0 * LATD + i];
  __syncthreads();

  const int u = tid & 127;
  const int grp = tid >> 7;       // 0/1 -> rows [0..8) / [8..16)
  const int r0 = grp * 8;
  if (u >= HD_DEC) return;

  float a0[8], a1[8], a2[8], a3[8];
  #pragma unroll
  for (int r = 0; r < 8; ++r) { a0[r] = 0.0f; a1[r] = 0.0f; a2[r] = 0.0f; a3[r] = 0.0f; }
  for (int k = 0; k < LATD; k += 4) {
    const float4 w0 = P1I[(k + 0) * 100 + u];
    const float4 w1 = P1I[(k + 1) * 100 + u];
    const float4 w2 = P1I[(k + 2) * 100 + u];
    const float4 w3 = P1I[(k + 3) * 100 + u];
    #pragma unroll
    for (int r = 0; r < 8; ++r) {
      const float4 xv = *reinterpret_cast<const float4*>(&zs[r0 + r][k]);
      GDOT(a0[r], x, w0, w1, w2, w3, xv);
      GDOT(a1[r], y, w0, w1, w2, w3, xv);
      GDOT(a2[r], z, w0, w1, w2, w3, xv);
      GDOT(a3[r], w, w0, w1, w2, w3, xv);
    }
  }
  #pragma unroll
  for (int r = 0; r < 8; ++r) {
    int b = b0 + r0 + r;
    zw1[b * 400 + u]       = a0[r];
    zw1[b * 400 + 100 + u] = a1[r];
    zw1[b * 400 + 200 + u] = a2[r];
    zw1[b * 400 + 300 + u] = a3[r];
  }
}

// ---------------- decoder cell step (z-part precomputed) ----------------
__global__ __launch_bounds__(256) void dec_cell_kernel(
    const float* __restrict__ zw1, const float* __restrict__ dlq,
    const float* __restrict__ macro,
    float* __restrict__ h1w, float* __restrict__ c1w,
    float* __restrict__ h2w, float* __restrict__ c2w,
    const float4* __restrict__ P1I, const float4* __restrict__ P1H, const float* __restrict__ be1,
    const float4* __restrict__ P2I, const float4* __restrict__ P2H, const float* __restrict__ be2,
    const float* __restrict__ Wg1T, const float* __restrict__ bg1,
    float* __restrict__ xbuf, int t)
{
  const int tid = threadIdx.x;
  const int b0 = blockIdx.x * 16;
  __shared__ float di[16][DTAIL];      // decinp k in [256..280): dlq 9 + mp 14 + pad
  __shared__ float h1s[16][HD_DEC];
  __shared__ float h2s[16][HD_DEC];

  for (int i = tid; i < 16 * DTAIL; i += 256) {
    int r = i / DTAIL, k = i - r * DTAIL;
    int b = b0 + r;
    float v;
    if (k < 9)       v = dlq[b * 9 + k];
    else if (k < 23) v = macro[(b * 12 + t) * 14 + (k - 9)];
    else             v = 0.0f;
    di[r][k] = v;
  }
  for (int i = tid; i < 16 * HD_DEC; i += 256) {
    int r = i / HD_DEC, k = i - r * HD_DEC;
    h1s[r][k] = h1w[(b0 + r) * HD_DEC + k];
    h2s[r][k] = h2w[(b0 + r) * HD_DEC + k];
  }

  const int u = tid & 127;
  const int grp = tid >> 7;       // 0/1 -> rows [0..8) / [8..16)
  const int r0 = grp * 8;
  const bool act = u < HD_DEC;

  float c1r[8], c2r[8];
  if (act) {
    #pragma unroll
    for (int r = 0; r < 8; ++r) {
      c1r[r] = c1w[(b0 + r0 + r) * HD_DEC + u];
      c2r[r] = c2w[(b0 + r0 + r) * HD_DEC + u];
    }
  }
  __syncthreads();

  // ---- LSTM1 gates: init = be1 + zw1 (z-part hoisted); k-loop over tail + h ----
  float a0[8], a1[8], a2[8], a3[8];
  if (act) {
    const float b0g = be1[u], b1g = be1[100 + u], b2g = be1[200 + u], b3g = be1[300 + u];
    #pragma unroll
    for (int r = 0; r < 8; ++r) {
      const float* zw = &zw1[(size_t)(b0 + r0 + r) * 400];
      a0[r] = b0g + zw[u];
      a1[r] = b1g + zw[100 + u];
      a2[r] = b2g + zw[200 + u];
      a3[r] = b3g + zw[300 + u];
    }
    for (int k = 0; k < DTAIL; k += 4) {
      const int kk = LATD + k;
      const float4 w0 = P1I[(kk + 0) * 100 + u];
      const float4 w1 = P1I[(kk + 1) * 100 + u];
      const float4 w2 = P1I[(kk + 2) * 100 + u];
      const float4 w3 = P1I[(kk + 3) * 100 + u];
      #pragma unroll
      for (int r = 0; r < 8; ++r) {
        const float4 xv = *reinterpret_cast<const float4*>(&di[r0 + r][k]);
        GDOT(a0[r], x, w0, w1, w2, w3, xv);
        GDOT(a1[r], y, w0, w1, w2, w3, xv);
        GDOT(a2[r], z, w0, w1, w2, w3, xv);
        GDOT(a3[r], w, w0, w1, w2, w3, xv);
      }
    }
    for (int k = 0; k < HD_DEC; k += 4) {
      const float4 w0 = P1H[(k + 0) * 100 + u];
      const float4 w1 = P1H[(k + 1) * 100 + u];
      const float4 w2 = P1H[(k + 2) * 100 + u];
      const float4 w3 = P1H[(k + 3) * 100 + u];
      #pragma unroll
      for (int r = 0; r < 8; ++r) {
        const float4 hv = *reinterpret_cast<const float4*>(&h1s[r0 + r][k]);
        GDOT(a0[r], x, w0, w1, w2, w3, hv);
        GDOT(a1[r], y, w0, w1, w2, w3, hv);
        GDOT(a2[r], z, w0, w1, w2, w3, hv);
        GDOT(a3[r], w, w0, w1, w2, w3, hv);
      }
    }
  }
  __syncthreads();                 // h1s reads complete
  if (act) {
    #pragma unroll
    for (int r = 0; r < 8; ++r) {
      float ig = sigf(a0[r]), fg = sigf(a1[r]), gg = tanhf(a2[r]), og = sigf(a3[r]);
      float cn = fg * c1r[r] + ig * gg;
      float hn = og * tanhf(cn);
      int b = b0 + r0 + r;
      h1s[r0 + r][u] = hn;
      h1w[b * HD_DEC + u] = hn;
      c1w[b * HD_DEC + u] = cn;
    }
  }
  __syncthreads();                 // new h1 visible

  // ---- LSTM2 gates (x = new h1, h = old h2) ----
  if (act) {
    const float b0g = be2[u], b1g = be2[100 + u], b2g = be2[200 + u], b3g = be2[300 + u];
    #pragma unroll
    for (int r = 0; r < 8; ++r) { a0[r] = b0g; a1[r] = b1g; a2[r] = b2g; a3[r] = b3g; }
    for (int k = 0; k < HD_DEC; k += 4) {
      const float4 w0 = P2I[(k + 0) * 100 + u];
      const float4 w1 = P2I[(k + 1) * 100 + u];
      const float4 w2 = P2I[(k + 2) * 100 + u];
      const float4 w3 = P2I[(k + 3) * 100 + u];
      #pragma unroll
      for (int r = 0; r < 8; ++r) {
        const float4 hv = *reinterpret_cast<const float4*>(&h1s[r0 + r][k]);
        GDOT(a0[r], x, w0, w1, w2, w3, hv);
        GDOT(a1[r], y, w0, w1, w2, w3, hv);
        GDOT(a2[r], z, w0, w1, w2, w3, hv);
        GDOT(a3[r], w, w0, w1, w2, w3, hv);
      }
    }
    for (int k = 0; k < HD_DEC; k += 4) {
      const float4 w0 = P2H[(k + 0) * 100 + u];
      const float4 w1 = P2H[(k + 1) * 100 + u];
      const float4 w2 = P2H[(k + 2) * 100 + u];
      const float4 w3 = P2H[(k + 3) * 100 + u];
      #pragma unroll
      for (int r = 0; r < 8; ++r) {
        const float4 hv = *reinterpret_cast<const float4*>(&h2s[r0 + r][k]);
        GDOT(a0[r], x, w0, w1, w2, w3, hv);
        GDOT(a1[r], y, w0, w1, w2, w3, hv);
        GDOT(a2[r], z, w0, w1, w2, w3, hv);
        GDOT(a3[r], w, w0, w1, w2, w3, hv);
      }
    }
  }
  __syncthreads();                 // h2s reads complete
  if (act) {
    #pragma unroll
    for (int r = 0; r < 8; ++r) {
      float ig = sigf(a0[r]), fg = sigf(a1[r]), gg = tanhf(a2[r]), og = sigf(a3[r]);
      float cn = fg * c2r[r] + ig * gg;
      float hn = og * tanhf(cn);
      int b = b0 + r0 + r;
      h2s[r0 + r][u] = hn;
      h2w[b * HD_DEC + u] = hn;
      c2w[b * HD_DEC + u] = cn;
    }
  }
  __syncthreads();                 // new h2 visible

  // ---- x = relu(h2 @ Wg1T + bg1) ----
  for (int p = tid; p < 16 * 25; p += 256) {
    int r = p / 25, cc = p - r * 25;
    float s = bg1[cc];
    for (int k = 0; k < HD_DEC; k += 4) {
      const float4 hv = *reinterpret_cast<const float4*>(&h2s[r][k]);
      s += hv.x * Wg1T[k * 25 + cc] + hv.y * Wg1T[(k + 1) * 25 + cc]
         + hv.z * Wg1T[(k + 2) * 25 + cc] + hv.w * Wg1T[(k + 3) * 25 + cc];
    }
    xbuf[(b0 + r) * 25 + cc] = fmaxf(s, 0.0f);
  }
}

// ---------------- decoder batchnorm stats ----------------
__global__ __launch_bounds__(256) void dec_stats_kernel(
    const float* __restrict__ xbuf, float* __restrict__ muv, float* __restrict__ rstdv)
{
  const int col = blockIdx.x;
  const int tid = threadIdx.x;
  __shared__ float red[256];
  float v[16];
  float s = 0.0f;
  #pragma unroll
  for (int i = 0; i < 16; ++i) { v[i] = xbuf[(tid + 256 * i) * 25 + col]; s += v[i]; }
  red[tid] = s; __syncthreads();
  for (int off = 128; off >= 1; off >>= 1) {
    if (tid < off) red[tid] += red[tid + off];
    __syncthreads();
  }
  float mean = red[0] / (float)B_SZ;
  __syncthreads();
  float s2 = 0.0f;
  #pragma unroll
  for (int i = 0; i < 16; ++i) { float d = v[i] - mean; s2 += d * d; }
  red[tid] = s2; __syncthreads();
  for (int off = 128; off >= 1; off >>= 1) {
    if (tid < off) red[tid] += red[tid + off];
    __syncthreads();
  }
  if (tid == 0) {
    muv[col] = mean;
    rstdv[col] = rsqrtf(red[0] / (float)B_SZ + 1e-5f);
  }
}

// ---------------- decoder normalize + output ----------------
__global__ __launch_bounds__(256) void dec_out_kernel(
    const float* __restrict__ xbuf, const float* __restrict__ muv, const float* __restrict__ rstdv,
    const float* __restrict__ gamma, const float* __restrict__ beta,
    const float* __restrict__ Wg2, const float* __restrict__ bg2,
    float* __restrict__ dlq, float* __restrict__ out, int t)
{
  int b = blockIdx.x * 256 + threadIdx.x;
  float xn[25];
  #pragma unroll
  for (int c = 0; c < 25; ++c)
    xn[c] = gamma[c] * (xbuf[b * 25 + c] - muv[c]) * rstdv[c] + beta[c];
  #pragma unroll
  for (int j = 0; j < 9; ++j) {
    float s = bg2[j];
    #pragma unroll
    for (int c = 0; c < 25; ++c) s += xn[c] * Wg2[j * 25 + c];
    dlq[b * 9 + j] = s;
    out[b * 108 + j * 12 + t] = s;
  }
}

// ---------------- host launch ----------------
extern "C" void kernel_launch(void* const* d_in, const int* in_sizes, int n_in,
                              void* d_out, int out_size, void* d_ws, size_t ws_size,
                              hipStream_t stream)
{
  const float* seq     = (const float*)d_in[0];
  const int*   seq_len = (const int*)  d_in[1];
  const int*   ymd     = (const int*)  d_in[2];
  const int*   acq     = (const int*)  d_in[3];
  const float* macro   = (const float*)d_in[4];
  const float* z_noise = (const float*)d_in[5];
  const float* Ea0 = (const float*)d_in[6];
  const float* Ea1 = (const float*)d_in[7];
  const float* Ea2 = (const float*)d_in[8];
  const float* Es0 = (const float*)d_in[9];
  const float* Es1 = (const float*)d_in[10];
  const float* Es2 = (const float*)d_in[11];
  const float* Wih_f = (const float*)d_in[12];
  const float* Whh_f = (const float*)d_in[13];
  const float* bih_f = (const float*)d_in[14];
  const float* bhh_f = (const float*)d_in[15];
  const float* Wih_b = (const float*)d_in[16];
  const float* Whh_b = (const float*)d_in[17];
  const float* bih_b = (const float*)d_in[18];
  const float* bhh_b = (const float*)d_in[19];
  const float* W_lat = (const float*)d_in[20];
  const float* b_lat = (const float*)d_in[21];
  const float* Wih1  = (const float*)d_in[22];
  const float* Whh1  = (const float*)d_in[23];
  const float* bih1  = (const float*)d_in[24];
  const float* bhh1  = (const float*)d_in[25];
  const float* Wih2  = (const float*)d_in[26];
  const float* Whh2  = (const float*)d_in[27];
  const float* bih2  = (const float*)d_in[28];
  const float* bhh2  = (const float*)d_in[29];
  const float* Wg1   = (const float*)d_in[30];
  const float* bg1   = (const float*)d_in[31];
  const float* gamma = (const float*)d_in[32];
  const float* beta  = (const float*)d_in[33];
  const float* Wg2   = (const float*)d_in[34];
  const float* bg2   = (const float*)d_in[35];

  float* ws  = (float*)d_ws;
  float* out = (float*)d_out;

  float* pwF  = ws + OFF_PW_F;
  float* pwB  = ws + OFF_PW_B;
  float* a0F  = ws + OFF_A0F;  float* a1F = ws + OFF_A1F;  float* a2F = ws + OFF_A2F;
  float* t0F  = ws + OFF_T0F;  float* t1F = ws + OFF_T1F;  float* t2F = ws + OFF_T2F;
  float* a0B  = ws + OFF_A0B;  float* a1B = ws + OFF_A1B;  float* a2B = ws + OFF_A2B;
  float* t0B  = ws + OFF_T0B;  float* t1B = ws + OFF_T1B;  float* t2B = ws + OFF_T2B;
  float* plat = ws + OFF_PLAT;
  float* p1i  = ws + OFF_P1I;
  float* p1h  = ws + OFF_P1H;
  float* p2i  = ws + OFF_P2I;
  float* p2h  = ws + OFF_P2H;
  float* wg1T = ws + OFF_WG1T;
  float* be_f = ws + OFF_BE_F;
  float* be_b = ws + OFF_BE_B;
  float* be1  = ws + OFF_BE1;
  float* be2  = ws + OFF_BE2;
  float* hf   = ws + OFF_HF;
  float* hb   = ws + OFF_HB;
  float* z    = ws + OFF_Z;
  float* h1w  = ws + OFF_H1;
  float* c1w  = ws + OFF_C1;
  float* h2w  = ws + OFF_H2;
  float* c2w  = ws + OFF_C2;
  float* dlq  = ws + OFF_DLQ;
  float* xbuf = ws + OFF_XBUF;
  float* muv  = ws + OFF_MU;
  float* rstdv= ws + OFF_RSTD;
  float* zw1  = ws + OFF_ZW1;

  PrepArgs pa;
  int ji = 0;
  auto JOB = [&](const float* a, const float* b, float* d, int p0, int p1, int p2, int p3, int m) {
    pa.j[ji].a = a; pa.j[ji].b = b; pa.j[ji].dst = d;
    pa.j[ji].p0 = p0; pa.j[ji].p1 = p1; pa.j[ji].p2 = p2; pa.j[ji].p3 = p3; pa.j[ji].mode = m; ++ji;
  };
  JOB(Wih_f, Whh_f, pwF, 0,0,0,0, 2);
  JOB(Wih_b, Whh_b, pwB, 0,0,0,0, 2);
  JOB(Ea0, Wih_f, a0F, 50, 16, 30, 0, 3);
  JOB(Ea1, Wih_f, a1F, 10,  8, 46, 0, 3);
  JOB(Ea2, Wih_f, a2F,  5,  4, 54, 0, 3);
  JOB(Es0, Wih_f, t0F, 30,  8, 58, 0, 3);
  JOB(Es1, Wih_f, t1F, 12,  4, 66, 0, 3);
  JOB(Es2, Wih_f, t2F, 31,  4, 70, 0, 3);
  JOB(Ea0, Wih_b, a0B, 50, 16, 30, 0, 3);
  JOB(Ea1, Wih_b, a1B, 10,  8, 46, 0, 3);
  JOB(Ea2, Wih_b, a2B,  5,  4, 54, 0, 3);
  JOB(Es0, Wih_b, t0B, 30,  8, 58, 0, 3);
  JOB(Es1, Wih_b, t1B, 12,  4, 66, 0, 3);
  JOB(Es2, Wih_b, t2B, 31,  4, 70, 0, 3);
  JOB(W_lat, nullptr, plat, 256, 256, 256, 2, 0);
  JOB(Wih1,  nullptr, p1i,  100, 279, 280, 4, 0);
  JOB(Whh1,  nullptr, p1h,  100, 100, 100, 4, 0);
  JOB(Wih2,  nullptr, p2i,  100, 100, 100, 4, 0);
  JOB(Whh2,  nullptr, p2h,  100, 100, 100, 4, 0);
  JOB(Wg1,   nullptr, wg1T, 25, 100, 100, 1, 0);
  JOB(bih_f, bhh_f, be_f, 1024, 0,0,0, 1);
  JOB(bih_b, bhh_b, be_b, 1024, 0,0,0, 1);
  JOB(bih1,  bhh1,  be1,  400, 0,0,0, 1);
  JOB(bih2,  bhh2,  be2,  400, 0,0,0, 1);

  prep_kernel<<<512, 256, 0, stream>>>(pa);

  enc_kernel<<<256, 1024, 0, stream>>>(
      seq, seq_len, ymd, acq,
      (const uint4*)pwF, (const uint4*)pwB,
      (const float4*)a0F, (const float4*)a1F, (const float4*)a2F,
      (const float4*)t0F, (const float4*)t1F, (const float4*)t2F,
      (const float4*)a0B, (const float4*)a1B, (const float4*)a2B,
      (const float4*)t0B, (const float4*)t1B, (const float4*)t2B,
      be_f, be_b, hf, hb);

  latent_kernel<<<256, 256, 0, stream>>>(
      hf, hb, (const float2*)plat, b_lat, z_noise, seq, seq_len,
      z, dlq, h1w, c1w, h2w, c2w);

  dec_zpre_kernel<<<256, 256, 0, stream>>>(z, (const float4*)p1i, zw1);

  for (int t = 0; t < 12; ++t) {
    dec_cell_kernel<<<256, 256, 0, stream>>>(
        zw1, dlq, macro, h1w, c1w, h2w, c2w,
        (const float4*)p1i, (const float4*)p1h, be1,
        (const float4*)p2i, (const float4*)p2h, be2, wg1T, bg1, xbuf, t);
    dec_stats_kernel<<<25, 256, 0, stream>>>(xbuf, muv, rstdv);
    dec_out_kernel<<<16, 256, 0, stream>>>(
        xbuf, muv, rstdv, gamma, beta, Wg2, bg2, dlq, out, t);
  }
}